// Round 3
// baseline (36034.811 us; speedup 1.0000x reference)
//
#include <hip/hip_runtime.h>
#include <hip/hip_cooperative_groups.h>
#include <math.h>

namespace cg = cooperative_groups;

#define NN 8192
#define DD 2048
#define KK 256
#define LOOP_BLOCKS 512   // 4 G-rows per block (one per wave)

// ---------- block reduce (256 threads, wave=64) ----------
__device__ __forceinline__ float blockReduceSum(float val, float* sdata) {
    for (int off = 32; off > 0; off >>= 1)
        val += __shfl_down(val, off, 64);
    int wid = threadIdx.x >> 6;
    int lane = threadIdx.x & 63;
    __syncthreads();                 // protect sdata from previous use
    if (lane == 0) sdata[wid] = val;
    __syncthreads();
    return sdata[0] + sdata[1] + sdata[2] + sdata[3];
}

// ---------- V0 [D][K] -> V0T [K][D] ----------
__global__ void ktranspose(const float* __restrict__ V0, float* __restrict__ V0T) {
    __shared__ float tile[32][33];
    int bx = blockIdx.x;
    int by = blockIdx.y;
    int tx = threadIdx.x % 32;
    int ty = threadIdx.x / 32;
    for (int r = ty; r < 32; r += 8)
        tile[r][tx] = V0[(size_t)(bx * 32 + r) * KK + by * 32 + tx];
    __syncthreads();
    for (int r = ty; r < 32; r += 8)
        V0T[(size_t)(by * 32 + r) * DD + bx * 32 + tx] = tile[tx][r];
}

// ---------- d0[k] = ||V0[:,k]|| ----------
__global__ void kd0(const float* __restrict__ V0T, float* __restrict__ d0) {
    __shared__ float sdata[4];
    int k = blockIdx.x;
    float acc = 0.f;
    for (int j = threadIdx.x; j < DD; j += 256) {
        float v = V0T[(size_t)k * DD + j];
        acc += v * v;
    }
    float s = blockReduceSum(acc, sdata);
    if (threadIdx.x == 0) d0[k] = sqrtf(s);
}

// ---------- G += x_chunk^T x_chunk, 128x128 triangle tiles, 8 N-chunks ----------
__global__ __launch_bounds__(256) void ksyrk(const float* __restrict__ x,
                                             float* __restrict__ G) {
    __shared__ float As[16][132];
    __shared__ float Bs[16][132];
    int t = blockIdx.x;                       // 0..135 triangle tiles of 16x16 grid
    int bj = (int)((sqrtf(8.0f * (float)t + 1.0f) - 1.0f) * 0.5f);
    while ((bj + 1) * (bj + 2) / 2 <= t) ++bj;
    while (bj * (bj + 1) / 2 > t) --bj;
    int bi = t - bj * (bj + 1) / 2;
    int a0 = bi * 128, b0 = bj * 128;
    int n0 = blockIdx.y * (NN / 8);
    int n1 = n0 + NN / 8;
    int tid = threadIdx.x;
    int lr = tid / 32, lc = (tid % 32) * 4;   // staging: row 0..7, col quad
    int tr = tid / 16, tc = tid % 16;         // 16x16 thread grid, 8x8 each
    float acc[8][8] = {};
    for (int n = n0; n < n1; n += 16) {
        *(float4*)&As[lr][lc]     = *(const float4*)&x[(size_t)(n + lr) * DD + a0 + lc];
        *(float4*)&As[lr + 8][lc] = *(const float4*)&x[(size_t)(n + lr + 8) * DD + a0 + lc];
        *(float4*)&Bs[lr][lc]     = *(const float4*)&x[(size_t)(n + lr) * DD + b0 + lc];
        *(float4*)&Bs[lr + 8][lc] = *(const float4*)&x[(size_t)(n + lr + 8) * DD + b0 + lc];
        __syncthreads();
        for (int kk = 0; kk < 16; ++kk) {
            float a[8], b[8];
            *(float4*)&a[0] = *(const float4*)&As[kk][tr * 8];
            *(float4*)&a[4] = *(const float4*)&As[kk][tr * 8 + 4];
            *(float4*)&b[0] = *(const float4*)&Bs[kk][tc * 8];
            *(float4*)&b[4] = *(const float4*)&Bs[kk][tc * 8 + 4];
            for (int i = 0; i < 8; ++i)
                for (int j = 0; j < 8; ++j)
                    acc[i][j] += a[i] * b[j];
        }
        __syncthreads();
    }
    for (int i = 0; i < 8; ++i) {
        int gr = a0 + tr * 8 + i;
        for (int j = 0; j < 8; ++j)
            atomicAdd(&G[(size_t)gr * DD + b0 + tc * 8 + j], acc[i][j]);
    }
}

// ---------- mirror upper 128-tiles to lower ----------
__global__ void kmirror(float* __restrict__ G) {
    __shared__ float tile[64][65];
    int bi = blockIdx.x, bj = blockIdx.y;
    if (bi >= bj) return;
    int tx = threadIdx.x % 64;
    int ty = threadIdx.x / 64;                // 0..3
    for (int si = 0; si < 2; ++si)
        for (int sj = 0; sj < 2; ++sj) {
            int r0 = bi * 128 + si * 64, c0 = bj * 128 + sj * 64;
            __syncthreads();
            for (int r = ty; r < 64; r += 4)
                tile[r][tx] = G[(size_t)(r0 + r) * DD + c0 + tx];
            __syncthreads();
            for (int r = ty; r < 64; r += 4)
                G[(size_t)(c0 + r) * DD + r0 + tx] = tile[tx][r];
        }
}

// ---------- persistent cooperative K-loop ----------
__global__ void __launch_bounds__(256, 2)
kloop(float* __restrict__ G, const float* __restrict__ V0T,
      const float* __restrict__ d0, float* __restrict__ Vn,
      float* __restrict__ g, float* __restrict__ s) {
    cg::grid_group grid = cg::this_grid();
    __shared__ float bufU[DD];   // u (phase A) -> vn (phase B)
    __shared__ float bufH[DD];   // h = g - c*vn
    __shared__ float bufW[DD];   // v0_next
    __shared__ float sdata[4];
    int tid = threadIdx.x;
    int wave = tid >> 6, lane = tid & 63;
    int row = blockIdx.x * 4 + wave;
    float* Gr = G + (size_t)row * DD;

    // init: s = G v0_0
    {
        for (int t = 0; t < 8; ++t) bufW[tid + t * 256] = V0T[tid + t * 256];
        __syncthreads();
        float a = 0.f;
        for (int c = 0; c < 8; ++c) {
            int idx = lane * 4 + c * 256;
            float4 gq = *(const float4*)(Gr + idx);
            float4 vq = *(const float4*)(bufW + idx);
            a += gq.x * vq.x + gq.y * vq.y + gq.z * vq.z + gq.w * vq.w;
        }
        for (int off = 32; off > 0; off >>= 1) a += __shfl_down(a, off, 64);
        if (lane == 0) s[row] = a;
    }
    grid.sync();

    for (int k = 0; k < KK; ++k) {
        // ---- phase A: u = 0.5 v + (0.5/d) s; vn = u/||u||; g = G vn ----
        const float* v = V0T + (size_t)k * DD;
        float cf = 0.5f / d0[k];
        float acc = 0.f;
        __syncthreads();                      // bufU reuse vs previous reads
        for (int t = 0; t < 8; ++t) {
            int j = tid + t * 256;
            float uj = 0.5f * v[j] + cf * s[j];
            bufU[j] = uj;
            acc += uj * uj;
        }
        float n2 = blockReduceSum(acc, sdata);   // barrier covers bufU writes
        float inv = 1.0f / sqrtf(n2);            // identical in every block
        if (blockIdx.x == 0) {
            for (int t = 0; t < 8; ++t) {
                int j = tid + t * 256;
                Vn[(size_t)k * DD + j] = bufU[j] * inv;
            }
        }
        {
            float a = 0.f;
            for (int c = 0; c < 8; ++c) {
                int idx = lane * 4 + c * 256;
                float4 gq = *(const float4*)(Gr + idx);
                float4 uq = *(const float4*)(bufU + idx);
                a += gq.x * uq.x + gq.y * uq.y + gq.z * uq.z + gq.w * uq.w;
            }
            for (int off = 32; off > 0; off >>= 1) a += __shfl_down(a, off, 64);
            if (lane == 0) g[row] = a * inv;     // g = G vn
        }
        grid.sync();
        if (k == KK - 1) break;

        // ---- phase B: G -= vn h^T + g vn^T; fused s_next = G' v0_{k+1} ----
        float accc = 0.f;
        for (int t = 0; t < 8; ++t) {
            int j = tid + t * 256;
            float vnj = bufU[j] * inv;           // vn from local u (no global read)
            bufU[j] = vnj;
            float gj = g[j];
            bufH[j] = gj;
            bufW[j] = V0T[(size_t)(k + 1) * DD + j];
            accc += vnj * gj;
        }
        float c2 = blockReduceSum(accc, sdata);  // barrier covers buf writes
        for (int t = 0; t < 8; ++t) {
            int j = tid + t * 256;
            bufH[j] -= c2 * bufU[j];
        }
        __syncthreads();
        float vni = bufU[row];
        float gi = g[row];
        float a2 = 0.f;
        for (int cc = 0; cc < 8; ++cc) {
            int idx = lane * 4 + cc * 256;
            float4 Gq = *(float4*)(Gr + idx);
            float4 hq = *(const float4*)(bufH + idx);
            float4 vq = *(const float4*)(bufU + idx);
            float4 wq = *(const float4*)(bufW + idx);
            Gq.x = Gq.x - vni * hq.x - gi * vq.x;
            Gq.y = Gq.y - vni * hq.y - gi * vq.y;
            Gq.z = Gq.z - vni * hq.z - gi * vq.z;
            Gq.w = Gq.w - vni * hq.w - gi * vq.w;
            a2 += Gq.x * wq.x + Gq.y * wq.y + Gq.z * wq.z + Gq.w * wq.w;
            *(float4*)(Gr + idx) = Gq;
        }
        for (int off = 32; off > 0; off >>= 1) a2 += __shfl_down(a2, off, 64);
        if (lane == 0) s[row] = a2;
        grid.sync();
    }
}

// ---------- out[N][K] = x . Vn^T  (64x64 tiles, fp32) ----------
__global__ void kout(const float* __restrict__ x, const float* __restrict__ Vn,
                     float* __restrict__ out) {
    __shared__ float As[32][68];
    __shared__ float Bs[32][68];
    int i0 = blockIdx.x * 64;
    int k0 = blockIdx.y * 64;
    int tid = threadIdx.x;
    int tr = tid / 16;
    int tc = tid % 16;
    float acc[4][4] = {};
    for (int j0 = 0; j0 < DD; j0 += 32) {
        int c = tid % 32;
        int r0 = tid / 32;
        for (int pass = 0; pass < 8; ++pass) {
            int rr = r0 + pass * 8;
            As[c][rr] = x[(size_t)(i0 + rr) * DD + j0 + c];
            Bs[c][rr] = Vn[(size_t)(k0 + rr) * DD + j0 + c];
        }
        __syncthreads();
        for (int kk = 0; kk < 32; ++kk) {
            float4 a4 = *(const float4*)&As[kk][tr * 4];
            float4 b4 = *(const float4*)&Bs[kk][tc * 4];
            float a[4] = {a4.x, a4.y, a4.z, a4.w};
            float b[4] = {b4.x, b4.y, b4.z, b4.w};
            for (int ar = 0; ar < 4; ++ar)
                for (int bc = 0; bc < 4; ++bc)
                    acc[ar][bc] += a[ar] * b[bc];
        }
        __syncthreads();
    }
    for (int ar = 0; ar < 4; ++ar) {
        float4 o = make_float4(acc[ar][0], acc[ar][1], acc[ar][2], acc[ar][3]);
        *(float4*)&out[(size_t)(i0 + tr * 4 + ar) * KK + k0 + tc * 4] = o;
    }
}

extern "C" void kernel_launch(void* const* d_in, const int* in_sizes, int n_in,
                              void* d_out, int out_size, void* d_ws, size_t ws_size,
                              hipStream_t stream) {
    const float* x  = (const float*)d_in[0];   // [N*D]
    const float* V0 = (const float*)d_in[1];   // [D*K]
    float* out = (float*)d_out;                // [N*K]

    float* G   = (float*)d_ws;                 // D*D
    float* V0T = G + (size_t)DD * DD;          // K*D
    float* Vn  = V0T + (size_t)KK * DD;        // K*D
    float* g   = Vn + (size_t)KK * DD;         // D
    float* sb  = g + DD;                       // D
    float* d0  = sb + DD;                      // K

    hipMemsetAsync(G, 0, (size_t)DD * DD * sizeof(float), stream);
    ktranspose<<<dim3(DD / 32, KK / 32), 256, 0, stream>>>(V0, V0T);
    kd0<<<KK, 256, 0, stream>>>(V0T, d0);
    ksyrk<<<dim3(136, 8), 256, 0, stream>>>(x, G);
    kmirror<<<dim3(16, 16), 256, 0, stream>>>(G);

    void* args[] = {(void*)&G, (void*)&V0T, (void*)&d0,
                    (void*)&Vn, (void*)&g, (void*)&sb};
    hipLaunchCooperativeKernel((void*)kloop, dim3(LOOP_BLOCKS), dim3(256),
                               args, 0, stream);

    kout<<<dim3(NN / 64, KK / 64), 256, 0, stream>>>(x, Vn, out);
}

// Round 4
// 23368.079 us; speedup vs baseline: 1.5421x; 1.5421x over previous
//
#include <hip/hip_runtime.h>
#include <hip/hip_cooperative_groups.h>
#include <math.h>

#define NN 8192
#define DD 2048
#define KK 256
#define LOOP_BLOCKS 512   // 4 G-rows per block (one per wave)

// ---------- block reduce (256 threads, wave=64) ----------
__device__ __forceinline__ float blockReduceSum(float val, float* sdata) {
    for (int off = 32; off > 0; off >>= 1)
        val += __shfl_down(val, off, 64);
    int wid = threadIdx.x >> 6;
    int lane = threadIdx.x & 63;
    __syncthreads();                 // protect sdata from previous use
    if (lane == 0) sdata[wid] = val;
    __syncthreads();
    return sdata[0] + sdata[1] + sdata[2] + sdata[3];
}

// ---------- hand-rolled grid barrier (monotonic index, flag array) ----------
__device__ __forceinline__ void gbar(unsigned* __restrict__ arrive,
                                     unsigned* __restrict__ gen, unsigned it) {
    __syncthreads();                 // all waves of this block done with prior phase
    int b = blockIdx.x;
    if (threadIdx.x == 0) {
        // release: orders all prior (atomic) stores before the flag becomes visible
        __hip_atomic_store(&arrive[b], it, __ATOMIC_RELEASE, __HIP_MEMORY_SCOPE_AGENT);
    }
    if (b == 0) {
        for (int s2 = threadIdx.x; s2 < LOOP_BLOCKS; s2 += 256) {
            while (__hip_atomic_load(&arrive[s2], __ATOMIC_ACQUIRE,
                                     __HIP_MEMORY_SCOPE_AGENT) < it)
                __builtin_amdgcn_s_sleep(2);
        }
        __syncthreads();
        if (threadIdx.x == 0)
            __hip_atomic_store(gen, it, __ATOMIC_RELEASE, __HIP_MEMORY_SCOPE_AGENT);
    } else {
        if (threadIdx.x == 0) {
            while (__hip_atomic_load(gen, __ATOMIC_ACQUIRE,
                                     __HIP_MEMORY_SCOPE_AGENT) < it)
                __builtin_amdgcn_s_sleep(2);
        }
        __syncthreads();
    }
}

__device__ __forceinline__ float aload(const float* p) {
    return __hip_atomic_load(p, __ATOMIC_RELAXED, __HIP_MEMORY_SCOPE_AGENT);
}
__device__ __forceinline__ void astore(float* p, float v) {
    __hip_atomic_store(p, v, __ATOMIC_RELAXED, __HIP_MEMORY_SCOPE_AGENT);
}

// ---------- V0 [D][K] -> V0T [K][D] ----------
__global__ void ktranspose(const float* __restrict__ V0, float* __restrict__ V0T) {
    __shared__ float tile[32][33];
    int bx = blockIdx.x;
    int by = blockIdx.y;
    int tx = threadIdx.x % 32;
    int ty = threadIdx.x / 32;
    for (int r = ty; r < 32; r += 8)
        tile[r][tx] = V0[(size_t)(bx * 32 + r) * KK + by * 32 + tx];
    __syncthreads();
    for (int r = ty; r < 32; r += 8)
        V0T[(size_t)(by * 32 + r) * DD + bx * 32 + tx] = tile[tx][r];
}

// ---------- d0[k] = ||V0[:,k]|| ----------
__global__ void kd0(const float* __restrict__ V0T, float* __restrict__ d0) {
    __shared__ float sdata[4];
    int k = blockIdx.x;
    float acc = 0.f;
    for (int j = threadIdx.x; j < DD; j += 256) {
        float v = V0T[(size_t)k * DD + j];
        acc += v * v;
    }
    float s = blockReduceSum(acc, sdata);
    if (threadIdx.x == 0) d0[k] = sqrtf(s);
}

// ---------- G += x_chunk^T x_chunk, 128x128 triangle tiles, 8 N-chunks ----------
__global__ __launch_bounds__(256) void ksyrk(const float* __restrict__ x,
                                             float* __restrict__ G) {
    __shared__ float As[16][132];
    __shared__ float Bs[16][132];
    int t = blockIdx.x;                       // 0..135 triangle tiles of 16x16 grid
    int bj = (int)((sqrtf(8.0f * (float)t + 1.0f) - 1.0f) * 0.5f);
    while ((bj + 1) * (bj + 2) / 2 <= t) ++bj;
    while (bj * (bj + 1) / 2 > t) --bj;
    int bi = t - bj * (bj + 1) / 2;
    int a0 = bi * 128, b0 = bj * 128;
    int n0 = blockIdx.y * (NN / 8);
    int n1 = n0 + NN / 8;
    int tid = threadIdx.x;
    int lr = tid / 32, lc = (tid % 32) * 4;   // staging: row 0..7, col quad
    int tr = tid / 16, tc = tid % 16;         // 16x16 thread grid, 8x8 each
    float acc[8][8] = {};
    for (int n = n0; n < n1; n += 16) {
        *(float4*)&As[lr][lc]     = *(const float4*)&x[(size_t)(n + lr) * DD + a0 + lc];
        *(float4*)&As[lr + 8][lc] = *(const float4*)&x[(size_t)(n + lr + 8) * DD + a0 + lc];
        *(float4*)&Bs[lr][lc]     = *(const float4*)&x[(size_t)(n + lr) * DD + b0 + lc];
        *(float4*)&Bs[lr + 8][lc] = *(const float4*)&x[(size_t)(n + lr + 8) * DD + b0 + lc];
        __syncthreads();
        for (int kk = 0; kk < 16; ++kk) {
            float a[8], b[8];
            *(float4*)&a[0] = *(const float4*)&As[kk][tr * 8];
            *(float4*)&a[4] = *(const float4*)&As[kk][tr * 8 + 4];
            *(float4*)&b[0] = *(const float4*)&Bs[kk][tc * 8];
            *(float4*)&b[4] = *(const float4*)&Bs[kk][tc * 8 + 4];
            for (int i = 0; i < 8; ++i)
                for (int j = 0; j < 8; ++j)
                    acc[i][j] += a[i] * b[j];
        }
        __syncthreads();
    }
    for (int i = 0; i < 8; ++i) {
        int gr = a0 + tr * 8 + i;
        for (int j = 0; j < 8; ++j)
            atomicAdd(&G[(size_t)gr * DD + b0 + tc * 8 + j], acc[i][j]);
    }
}

// ---------- mirror upper 128-tiles to lower ----------
__global__ void kmirror(float* __restrict__ G) {
    __shared__ float tile[64][65];
    int bi = blockIdx.x, bj = blockIdx.y;
    if (bi >= bj) return;
    int tx = threadIdx.x % 64;
    int ty = threadIdx.x / 64;                // 0..3
    for (int si = 0; si < 2; ++si)
        for (int sj = 0; sj < 2; ++sj) {
            int r0 = bi * 128 + si * 64, c0 = bj * 128 + sj * 64;
            __syncthreads();
            for (int r = ty; r < 64; r += 4)
                tile[r][tx] = G[(size_t)(r0 + r) * DD + c0 + tx];
            __syncthreads();
            for (int r = ty; r < 64; r += 4)
                G[(size_t)(c0 + r) * DD + r0 + tx] = tile[tx][r];
        }
}

// ---------- persistent K-loop with custom barrier ----------
__global__ void __launch_bounds__(256, 2)
kloop(float* __restrict__ G, const float* __restrict__ V0T,
      const float* __restrict__ d0, float* __restrict__ Vn,
      float* __restrict__ g, float* __restrict__ s,
      unsigned* __restrict__ arrive, unsigned* __restrict__ gen) {
    __shared__ float bufU[DD];   // u (phase A) -> vn (phase B)
    __shared__ float bufH[DD];   // h = g - c*vn
    __shared__ float bufW[DD];   // v0_next
    __shared__ float sdata[4];
    int tid = threadIdx.x;
    int wave = tid >> 6, lane = tid & 63;
    int row = blockIdx.x * 4 + wave;
    float* Gr = G + (size_t)row * DD;   // block-private rows: plain, L2-cached
    unsigned it = 0;

    // init: s = G v0_0
    {
        for (int t = 0; t < 8; ++t) bufW[tid + t * 256] = V0T[tid + t * 256];
        __syncthreads();
        float a = 0.f;
        for (int c = 0; c < 8; ++c) {
            int idx = lane * 4 + c * 256;
            float4 gq = *(const float4*)(Gr + idx);
            float4 vq = *(const float4*)(bufW + idx);
            a += gq.x * vq.x + gq.y * vq.y + gq.z * vq.z + gq.w * vq.w;
        }
        for (int off = 32; off > 0; off >>= 1) a += __shfl_down(a, off, 64);
        if (lane == 0) astore(&s[row], a);
    }
    gbar(arrive, gen, ++it);

    for (int k = 0; k < KK; ++k) {
        // ---- phase A: u = 0.5 v + (0.5/d) s; vn = u/||u||; g = G vn ----
        const float* v = V0T + (size_t)k * DD;
        float cf = 0.5f / d0[k];
        float acc = 0.f;
        __syncthreads();                      // bufU reuse vs previous reads
        for (int t = 0; t < 8; ++t) {
            int j = tid + t * 256;
            float uj = 0.5f * v[j] + cf * aload(&s[j]);
            bufU[j] = uj;
            acc += uj * uj;
        }
        float n2 = blockReduceSum(acc, sdata);   // barrier covers bufU writes
        float inv = 1.0f / sqrtf(n2);            // identical in every block
        if (blockIdx.x == 0) {
            for (int t = 0; t < 8; ++t) {
                int j = tid + t * 256;
                Vn[(size_t)k * DD + j] = bufU[j] * inv;
            }
        }
        {
            float a = 0.f;
            for (int c = 0; c < 8; ++c) {
                int idx = lane * 4 + c * 256;
                float4 gq = *(const float4*)(Gr + idx);
                float4 uq = *(const float4*)(bufU + idx);
                a += gq.x * uq.x + gq.y * uq.y + gq.z * uq.z + gq.w * uq.w;
            }
            for (int off = 32; off > 0; off >>= 1) a += __shfl_down(a, off, 64);
            if (lane == 0) astore(&g[row], a * inv);   // g = G vn
        }
        gbar(arrive, gen, ++it);
        if (k == KK - 1) break;

        // ---- phase B: G -= vn h^T + g vn^T; fused s_next = G' v0_{k+1} ----
        float accc = 0.f;
        for (int t = 0; t < 8; ++t) {
            int j = tid + t * 256;
            float vnj = bufU[j] * inv;           // vn from local u (no global read)
            bufU[j] = vnj;
            float gj = aload(&g[j]);
            bufH[j] = gj;
            bufW[j] = V0T[(size_t)(k + 1) * DD + j];
            accc += vnj * gj;
        }
        float c2 = blockReduceSum(accc, sdata);  // barrier covers buf writes
        for (int t = 0; t < 8; ++t) {
            int j = tid + t * 256;
            bufH[j] -= c2 * bufU[j];
        }
        __syncthreads();
        float vni = bufU[row];
        float gi = bufH[row] + c2 * vni;         // = g[row], from LDS (no reload)
        float a2 = 0.f;
        for (int cc = 0; cc < 8; ++cc) {
            int idx = lane * 4 + cc * 256;
            float4 Gq = *(float4*)(Gr + idx);
            float4 hq = *(const float4*)(bufH + idx);
            float4 vq = *(const float4*)(bufU + idx);
            float4 wq = *(const float4*)(bufW + idx);
            Gq.x = Gq.x - vni * hq.x - gi * vq.x;
            Gq.y = Gq.y - vni * hq.y - gi * vq.y;
            Gq.z = Gq.z - vni * hq.z - gi * vq.z;
            Gq.w = Gq.w - vni * hq.w - gi * vq.w;
            a2 += Gq.x * wq.x + Gq.y * wq.y + Gq.z * wq.z + Gq.w * wq.w;
            *(float4*)(Gr + idx) = Gq;
        }
        for (int off = 32; off > 0; off >>= 1) a2 += __shfl_down(a2, off, 64);
        if (lane == 0) astore(&s[row], a2);
        gbar(arrive, gen, ++it);
    }
}

// ---------- out[N][K] = x . Vn^T  (64x64 tiles, fp32) ----------
__global__ void kout(const float* __restrict__ x, const float* __restrict__ Vn,
                     float* __restrict__ out) {
    __shared__ float As[32][68];
    __shared__ float Bs[32][68];
    int i0 = blockIdx.x * 64;
    int k0 = blockIdx.y * 64;
    int tid = threadIdx.x;
    int tr = tid / 16;
    int tc = tid % 16;
    float acc[4][4] = {};
    for (int j0 = 0; j0 < DD; j0 += 32) {
        int c = tid % 32;
        int r0 = tid / 32;
        for (int pass = 0; pass < 8; ++pass) {
            int rr = r0 + pass * 8;
            As[c][rr] = x[(size_t)(i0 + rr) * DD + j0 + c];
            Bs[c][rr] = Vn[(size_t)(k0 + rr) * DD + j0 + c];
        }
        __syncthreads();
        for (int kk = 0; kk < 32; ++kk) {
            float4 a4 = *(const float4*)&As[kk][tr * 4];
            float4 b4 = *(const float4*)&Bs[kk][tc * 4];
            float a[4] = {a4.x, a4.y, a4.z, a4.w};
            float b[4] = {b4.x, b4.y, b4.z, b4.w};
            for (int ar = 0; ar < 4; ++ar)
                for (int bc = 0; bc < 4; ++bc)
                    acc[ar][bc] += a[ar] * b[bc];
        }
        __syncthreads();
    }
    for (int ar = 0; ar < 4; ++ar) {
        float4 o = make_float4(acc[ar][0], acc[ar][1], acc[ar][2], acc[ar][3]);
        *(float4*)&out[(size_t)(i0 + tr * 4 + ar) * KK + k0 + tc * 4] = o;
    }
}

extern "C" void kernel_launch(void* const* d_in, const int* in_sizes, int n_in,
                              void* d_out, int out_size, void* d_ws, size_t ws_size,
                              hipStream_t stream) {
    const float* x  = (const float*)d_in[0];   // [N*D]
    const float* V0 = (const float*)d_in[1];   // [D*K]
    float* out = (float*)d_out;                // [N*K]

    float* G   = (float*)d_ws;                 // D*D
    float* V0T = G + (size_t)DD * DD;          // K*D
    float* Vn  = V0T + (size_t)KK * DD;        // K*D
    float* g   = Vn + (size_t)KK * DD;         // D
    float* sb  = g + DD;                       // D
    float* d0  = sb + DD;                      // K
    unsigned* arrive = (unsigned*)(d0 + KK);   // LOOP_BLOCKS
    unsigned* gen    = arrive + LOOP_BLOCKS;   // 1 (+pad)

    hipMemsetAsync(G, 0, (size_t)DD * DD * sizeof(float), stream);
    hipMemsetAsync(arrive, 0, (LOOP_BLOCKS + 32) * sizeof(unsigned), stream);
    ktranspose<<<dim3(DD / 32, KK / 32), 256, 0, stream>>>(V0, V0T);
    kd0<<<KK, 256, 0, stream>>>(V0T, d0);
    ksyrk<<<dim3(136, 8), 256, 0, stream>>>(x, G);
    kmirror<<<dim3(16, 16), 256, 0, stream>>>(G);

    void* args[] = {(void*)&G, (void*)&V0T, (void*)&d0, (void*)&Vn,
                    (void*)&g, (void*)&sb, (void*)&arrive, (void*)&gen};
    hipLaunchCooperativeKernel((void*)kloop, dim3(LOOP_BLOCKS), dim3(256),
                               args, 0, stream);

    kout<<<dim3(NN / 64, KK / 64), 256, 0, stream>>>(x, Vn, out);
}

// Round 5
// 5265.121 us; speedup vs baseline: 6.8441x; 4.4383x over previous
//
#include <hip/hip_runtime.h>
#include <hip/hip_cooperative_groups.h>
#include <math.h>

#define NN 8192
#define DD 2048
#define KK 256
#define LOOP_BLOCKS 512   // 4 G-rows per block (one per wave)

// ---------- block reduce (256 threads, wave=64) ----------
__device__ __forceinline__ float blockReduceSum(float val, float* sdata) {
    for (int off = 32; off > 0; off >>= 1)
        val += __shfl_down(val, off, 64);
    int wid = threadIdx.x >> 6;
    int lane = threadIdx.x & 63;
    __syncthreads();                 // protect sdata from previous use
    if (lane == 0) sdata[wid] = val;
    __syncthreads();
    return sdata[0] + sdata[1] + sdata[2] + sdata[3];
}

// ---------- cross-block primitives: RELAXED agent atomics only ----------
// Relaxed agent-scope atomics use per-access read/write-through (sc bits) and
// emit NO cache-wide invalidate/writeback — G stays dirty in each XCD's L2.
__device__ __forceinline__ float aload(const float* p) {
    return __hip_atomic_load(p, __ATOMIC_RELAXED, __HIP_MEMORY_SCOPE_AGENT);
}
__device__ __forceinline__ void astore(float* p, float v) {
    __hip_atomic_store(p, v, __ATOMIC_RELAXED, __HIP_MEMORY_SCOPE_AGENT);
}

// single-hop grid barrier, monotonic index, no acquire/release cache ops.
// Release semantics built manually: each wave drains its write-through stores
// (s_waitcnt 0), block joins (__syncthreads), then the flag is published.
__device__ __forceinline__ void gbar(unsigned* __restrict__ arrive, unsigned it) {
    __atomic_signal_fence(__ATOMIC_SEQ_CST);
    __builtin_amdgcn_s_waitcnt(0);        // this wave's sc-stores reached IC
    __syncthreads();                       // all waves of block drained
    if (threadIdx.x == 0)
        __hip_atomic_store(&arrive[blockIdx.x], it,
                           __ATOMIC_RELAXED, __HIP_MEMORY_SCOPE_AGENT);
    for (int i = threadIdx.x; i < LOOP_BLOCKS; i += 256) {
        while (__hip_atomic_load(&arrive[i], __ATOMIC_RELAXED,
                                 __HIP_MEMORY_SCOPE_AGENT) < it)
            __builtin_amdgcn_s_sleep(4);
    }
    __syncthreads();
    __atomic_signal_fence(__ATOMIC_SEQ_CST);
}

// ---------- V0 [D][K] -> V0T [K][D] ----------
__global__ void ktranspose(const float* __restrict__ V0, float* __restrict__ V0T) {
    __shared__ float tile[32][33];
    int bx = blockIdx.x;
    int by = blockIdx.y;
    int tx = threadIdx.x % 32;
    int ty = threadIdx.x / 32;
    for (int r = ty; r < 32; r += 8)
        tile[r][tx] = V0[(size_t)(bx * 32 + r) * KK + by * 32 + tx];
    __syncthreads();
    for (int r = ty; r < 32; r += 8)
        V0T[(size_t)(by * 32 + r) * DD + bx * 32 + tx] = tile[tx][r];
}

// ---------- d0[k] = ||V0[:,k]|| ----------
__global__ void kd0(const float* __restrict__ V0T, float* __restrict__ d0) {
    __shared__ float sdata[4];
    int k = blockIdx.x;
    float acc = 0.f;
    for (int j = threadIdx.x; j < DD; j += 256) {
        float v = V0T[(size_t)k * DD + j];
        acc += v * v;
    }
    float s = blockReduceSum(acc, sdata);
    if (threadIdx.x == 0) d0[k] = sqrtf(s);
}

// ---------- G += x_chunk^T x_chunk, 128x128 triangle tiles, 8 N-chunks ----------
__global__ __launch_bounds__(256) void ksyrk(const float* __restrict__ x,
                                             float* __restrict__ G) {
    __shared__ float As[16][132];
    __shared__ float Bs[16][132];
    int t = blockIdx.x;                       // 0..135 triangle tiles of 16x16 grid
    int bj = (int)((sqrtf(8.0f * (float)t + 1.0f) - 1.0f) * 0.5f);
    while ((bj + 1) * (bj + 2) / 2 <= t) ++bj;
    while (bj * (bj + 1) / 2 > t) --bj;
    int bi = t - bj * (bj + 1) / 2;
    int a0 = bi * 128, b0 = bj * 128;
    int n0 = blockIdx.y * (NN / 8);
    int n1 = n0 + NN / 8;
    int tid = threadIdx.x;
    int lr = tid / 32, lc = (tid % 32) * 4;   // staging: row 0..7, col quad
    int tr = tid / 16, tc = tid % 16;         // 16x16 thread grid, 8x8 each
    float acc[8][8] = {};
    for (int n = n0; n < n1; n += 16) {
        *(float4*)&As[lr][lc]     = *(const float4*)&x[(size_t)(n + lr) * DD + a0 + lc];
        *(float4*)&As[lr + 8][lc] = *(const float4*)&x[(size_t)(n + lr + 8) * DD + a0 + lc];
        *(float4*)&Bs[lr][lc]     = *(const float4*)&x[(size_t)(n + lr) * DD + b0 + lc];
        *(float4*)&Bs[lr + 8][lc] = *(const float4*)&x[(size_t)(n + lr + 8) * DD + b0 + lc];
        __syncthreads();
        for (int kk = 0; kk < 16; ++kk) {
            float a[8], b[8];
            *(float4*)&a[0] = *(const float4*)&As[kk][tr * 8];
            *(float4*)&a[4] = *(const float4*)&As[kk][tr * 8 + 4];
            *(float4*)&b[0] = *(const float4*)&Bs[kk][tc * 8];
            *(float4*)&b[4] = *(const float4*)&Bs[kk][tc * 8 + 4];
            for (int i = 0; i < 8; ++i)
                for (int j = 0; j < 8; ++j)
                    acc[i][j] += a[i] * b[j];
        }
        __syncthreads();
    }
    for (int i = 0; i < 8; ++i) {
        int gr = a0 + tr * 8 + i;
        for (int j = 0; j < 8; ++j)
            atomicAdd(&G[(size_t)gr * DD + b0 + tc * 8 + j], acc[i][j]);
    }
}

// ---------- mirror upper 128-tiles to lower ----------
__global__ void kmirror(float* __restrict__ G) {
    __shared__ float tile[64][65];
    int bi = blockIdx.x, bj = blockIdx.y;
    if (bi >= bj) return;
    int tx = threadIdx.x % 64;
    int ty = threadIdx.x / 64;                // 0..3
    for (int si = 0; si < 2; ++si)
        for (int sj = 0; sj < 2; ++sj) {
            int r0 = bi * 128 + si * 64, c0 = bj * 128 + sj * 64;
            __syncthreads();
            for (int r = ty; r < 64; r += 4)
                tile[r][tx] = G[(size_t)(r0 + r) * DD + c0 + tx];
            __syncthreads();
            for (int r = ty; r < 64; r += 4)
                G[(size_t)(c0 + r) * DD + r0 + tx] = tile[tx][r];
        }
}

// ---------- persistent K-loop, relaxed-atomic barrier, L2-resident G ----------
__global__ void __launch_bounds__(256, 2)
kloop(float* __restrict__ G, const float* __restrict__ V0T,
      const float* __restrict__ d0, float* __restrict__ Vn,
      float* __restrict__ g, float* __restrict__ s,
      unsigned* __restrict__ arrive) {
    __shared__ float bufU[DD];   // u (phase A) -> vn (phase B)
    __shared__ float bufH[DD];   // h = g - c*vn
    __shared__ float bufW[DD];   // v0_next
    __shared__ float sdata[4];
    int tid = threadIdx.x;
    int wave = tid >> 6, lane = tid & 63;
    int row = blockIdx.x * 4 + wave;
    float* Gr = G + (size_t)row * DD;   // block-private rows: plain, stays in L2
    unsigned it = 0;

    // init: s = G v0_0
    {
        for (int t = 0; t < 8; ++t) bufW[tid + t * 256] = V0T[tid + t * 256];
        __syncthreads();
        float a = 0.f;
        for (int c = 0; c < 8; ++c) {
            int idx = lane * 4 + c * 256;
            float4 gq = *(const float4*)(Gr + idx);
            float4 vq = *(const float4*)(bufW + idx);
            a += gq.x * vq.x + gq.y * vq.y + gq.z * vq.z + gq.w * vq.w;
        }
        for (int off = 32; off > 0; off >>= 1) a += __shfl_down(a, off, 64);
        if (lane == 0) astore(&s[row], a);
    }
    gbar(arrive, ++it);

    for (int k = 0; k < KK; ++k) {
        // ---- phase A: u = 0.5 v + (0.5/d) s; vn = u/||u||; g = G vn ----
        const float* v = V0T + (size_t)k * DD;
        float cf = 0.5f / d0[k];
        float acc = 0.f;
        __syncthreads();                      // bufU reuse vs previous reads
        for (int t = 0; t < 8; ++t) {
            int j = tid + t * 256;
            float uj = 0.5f * v[j] + cf * aload(&s[j]);
            bufU[j] = uj;
            acc += uj * uj;
        }
        float n2 = blockReduceSum(acc, sdata);   // barrier covers bufU writes
        float inv = 1.0f / sqrtf(n2);            // identical in every block
        if (blockIdx.x == 0) {
            for (int t = 0; t < 8; ++t) {
                int j = tid + t * 256;
                Vn[(size_t)k * DD + j] = bufU[j] * inv;
            }
        }
        {
            float a = 0.f;
            for (int c = 0; c < 8; ++c) {
                int idx = lane * 4 + c * 256;
                float4 gq = *(const float4*)(Gr + idx);
                float4 uq = *(const float4*)(bufU + idx);
                a += gq.x * uq.x + gq.y * uq.y + gq.z * uq.z + gq.w * uq.w;
            }
            for (int off = 32; off > 0; off >>= 1) a += __shfl_down(a, off, 64);
            if (lane == 0) astore(&g[row], a * inv);   // g = G vn
        }
        gbar(arrive, ++it);
        if (k == KK - 1) break;

        // ---- phase B: G -= vn h^T + g vn^T; fused s_next = G' v0_{k+1} ----
        float accc = 0.f;
        for (int t = 0; t < 8; ++t) {
            int j = tid + t * 256;
            float vnj = bufU[j] * inv;           // vn from local u (no global read)
            bufU[j] = vnj;
            float gj = aload(&g[j]);
            bufH[j] = gj;
            bufW[j] = V0T[(size_t)(k + 1) * DD + j];
            accc += vnj * gj;
        }
        float c2 = blockReduceSum(accc, sdata);  // barrier covers buf writes
        for (int t = 0; t < 8; ++t) {
            int j = tid + t * 256;
            bufH[j] -= c2 * bufU[j];
        }
        __syncthreads();
        float vni = bufU[row];
        float gi = bufH[row] + c2 * vni;         // = g[row], from LDS (no reload)
        float a2 = 0.f;
        for (int cc = 0; cc < 8; ++cc) {
            int idx = lane * 4 + cc * 256;
            float4 Gq = *(float4*)(Gr + idx);
            float4 hq = *(const float4*)(bufH + idx);
            float4 vq = *(const float4*)(bufU + idx);
            float4 wq = *(const float4*)(bufW + idx);
            Gq.x = Gq.x - vni * hq.x - gi * vq.x;
            Gq.y = Gq.y - vni * hq.y - gi * vq.y;
            Gq.z = Gq.z - vni * hq.z - gi * vq.z;
            Gq.w = Gq.w - vni * hq.w - gi * vq.w;
            a2 += Gq.x * wq.x + Gq.y * wq.y + Gq.z * wq.z + Gq.w * wq.w;
            *(float4*)(Gr + idx) = Gq;
        }
        for (int off = 32; off > 0; off >>= 1) a2 += __shfl_down(a2, off, 64);
        if (lane == 0) astore(&s[row], a2);
        gbar(arrive, ++it);
    }
}

// ---------- out[N][K] = x . Vn^T  (64x64 tiles, fp32) ----------
__global__ void kout(const float* __restrict__ x, const float* __restrict__ Vn,
                     float* __restrict__ out) {
    __shared__ float As[32][68];
    __shared__ float Bs[32][68];
    int i0 = blockIdx.x * 64;
    int k0 = blockIdx.y * 64;
    int tid = threadIdx.x;
    int tr = tid / 16;
    int tc = tid % 16;
    float acc[4][4] = {};
    for (int j0 = 0; j0 < DD; j0 += 32) {
        int c = tid % 32;
        int r0 = tid / 32;
        for (int pass = 0; pass < 8; ++pass) {
            int rr = r0 + pass * 8;
            As[c][rr] = x[(size_t)(i0 + rr) * DD + j0 + c];
            Bs[c][rr] = Vn[(size_t)(k0 + rr) * DD + j0 + c];
        }
        __syncthreads();
        for (int kk = 0; kk < 32; ++kk) {
            float4 a4 = *(const float4*)&As[kk][tr * 4];
            float4 b4 = *(const float4*)&Bs[kk][tc * 4];
            float a[4] = {a4.x, a4.y, a4.z, a4.w};
            float b[4] = {b4.x, b4.y, b4.z, b4.w};
            for (int ar = 0; ar < 4; ++ar)
                for (int bc = 0; bc < 4; ++bc)
                    acc[ar][bc] += a[ar] * b[bc];
        }
        __syncthreads();
    }
    for (int ar = 0; ar < 4; ++ar) {
        float4 o = make_float4(acc[ar][0], acc[ar][1], acc[ar][2], acc[ar][3]);
        *(float4*)&out[(size_t)(i0 + tr * 4 + ar) * KK + k0 + tc * 4] = o;
    }
}

extern "C" void kernel_launch(void* const* d_in, const int* in_sizes, int n_in,
                              void* d_out, int out_size, void* d_ws, size_t ws_size,
                              hipStream_t stream) {
    const float* x  = (const float*)d_in[0];   // [N*D]
    const float* V0 = (const float*)d_in[1];   // [D*K]
    float* out = (float*)d_out;                // [N*K]

    float* G   = (float*)d_ws;                 // D*D
    float* V0T = G + (size_t)DD * DD;          // K*D
    float* Vn  = V0T + (size_t)KK * DD;        // K*D
    float* g   = Vn + (size_t)KK * DD;         // D
    float* sb  = g + DD;                       // D
    float* d0  = sb + DD;                      // K
    unsigned* arrive = (unsigned*)(d0 + KK);   // LOOP_BLOCKS flags

    hipMemsetAsync(G, 0, (size_t)DD * DD * sizeof(float), stream);
    hipMemsetAsync(arrive, 0, LOOP_BLOCKS * sizeof(unsigned), stream);
    ktranspose<<<dim3(DD / 32, KK / 32), 256, 0, stream>>>(V0, V0T);
    kd0<<<KK, 256, 0, stream>>>(V0T, d0);
    ksyrk<<<dim3(136, 8), 256, 0, stream>>>(x, G);
    kmirror<<<dim3(16, 16), 256, 0, stream>>>(G);

    void* args[] = {(void*)&G, (void*)&V0T, (void*)&d0, (void*)&Vn,
                    (void*)&g, (void*)&sb, (void*)&arrive};
    hipLaunchCooperativeKernel((void*)kloop, dim3(LOOP_BLOCKS), dim3(256),
                               args, 0, stream);

    kout<<<dim3(NN / 64, KK / 64), 256, 0, stream>>>(x, Vn, out);
}

// Round 6
// 5208.841 us; speedup vs baseline: 6.9180x; 1.0108x over previous
//
#include <hip/hip_runtime.h>
#include <hip/hip_cooperative_groups.h>
#include <math.h>

#define NN 8192
#define DD 2048
#define KK 256
#define LOOP_BLOCKS 256   // 1 block/CU; 8 G-rows per block (2 per wave)

// ---------- block reduce (256 threads, wave=64) ----------
__device__ __forceinline__ float blockReduceSum(float val, float* sdata) {
    for (int off = 32; off > 0; off >>= 1)
        val += __shfl_down(val, off, 64);
    int wid = threadIdx.x >> 6;
    int lane = threadIdx.x & 63;
    __syncthreads();                 // protect sdata from previous use
    if (lane == 0) sdata[wid] = val;
    __syncthreads();
    return sdata[0] + sdata[1] + sdata[2] + sdata[3];
}

// ---------- cross-block primitives: RELAXED agent atomics only ----------
// Relaxed agent-scope atomics read/write through to the coherence point with
// NO cache-wide invalidate/writeback — block-private G stays dirty in L2.
__device__ __forceinline__ float aload(const float* p) {
    return __hip_atomic_load(p, __ATOMIC_RELAXED, __HIP_MEMORY_SCOPE_AGENT);
}
__device__ __forceinline__ void astore(float* p, float v) {
    __hip_atomic_store(p, v, __ATOMIC_RELAXED, __HIP_MEMORY_SCOPE_AGENT);
}
__device__ __forceinline__ unsigned aloadu(const unsigned* p) {
    return __hip_atomic_load(p, __ATOMIC_RELAXED, __HIP_MEMORY_SCOPE_AGENT);
}
__device__ __forceinline__ void astoreu(unsigned* p, unsigned v) {
    __hip_atomic_store(p, v, __ATOMIC_RELAXED, __HIP_MEMORY_SCOPE_AGENT);
}

// Two-hop grid barrier, monotonic index. Release = per-wave s_waitcnt drain +
// __syncthreads before flag publish. Poll traffic: block0-wave0 polls 256
// flags (4/lane); everyone else polls ONE gen word with thread 0.
__device__ __forceinline__ void gbar(unsigned* __restrict__ arrive,
                                     unsigned* __restrict__ gen, unsigned it) {
    __atomic_signal_fence(__ATOMIC_SEQ_CST);
    __builtin_amdgcn_s_waitcnt(0);        // this wave's sc-stores reached IC
    __syncthreads();                       // all waves of block drained
    int tid = threadIdx.x;
    if (tid == 0)
        astoreu(&arrive[blockIdx.x], it);
    if (blockIdx.x == 0) {
        if (tid < 64) {
            int base = tid * 4;
            for (;;) {
                unsigned a0 = aloadu(&arrive[base + 0]);
                unsigned a1 = aloadu(&arrive[base + 1]);
                unsigned a2 = aloadu(&arrive[base + 2]);
                unsigned a3 = aloadu(&arrive[base + 3]);
                if (a0 >= it && a1 >= it && a2 >= it && a3 >= it) break;
                __builtin_amdgcn_s_sleep(1);
            }
        }
        __syncthreads();
        if (tid == 0) astoreu(gen, it);
    } else {
        if (tid == 0) {
            while (aloadu(gen) < it)
                __builtin_amdgcn_s_sleep(1);
        }
        __syncthreads();
    }
    __atomic_signal_fence(__ATOMIC_SEQ_CST);
}

// ---------- V0 [D][K] -> V0T [K][D] ----------
__global__ void ktranspose(const float* __restrict__ V0, float* __restrict__ V0T) {
    __shared__ float tile[32][33];
    int bx = blockIdx.x;
    int by = blockIdx.y;
    int tx = threadIdx.x % 32;
    int ty = threadIdx.x / 32;
    for (int r = ty; r < 32; r += 8)
        tile[r][tx] = V0[(size_t)(bx * 32 + r) * KK + by * 32 + tx];
    __syncthreads();
    for (int r = ty; r < 32; r += 8)
        V0T[(size_t)(by * 32 + r) * DD + bx * 32 + tx] = tile[tx][r];
}

// ---------- d0[k] = ||V0[:,k]|| ----------
__global__ void kd0(const float* __restrict__ V0T, float* __restrict__ d0) {
    __shared__ float sdata[4];
    int k = blockIdx.x;
    float acc = 0.f;
    for (int j = threadIdx.x; j < DD; j += 256) {
        float v = V0T[(size_t)k * DD + j];
        acc += v * v;
    }
    float s = blockReduceSum(acc, sdata);
    if (threadIdx.x == 0) d0[k] = sqrtf(s);
}

// ---------- G += x_chunk^T x_chunk, 128x128 triangle tiles, 8 N-chunks ----------
__global__ __launch_bounds__(256) void ksyrk(const float* __restrict__ x,
                                             float* __restrict__ G) {
    __shared__ float As[16][132];
    __shared__ float Bs[16][132];
    int t = blockIdx.x;                       // 0..135 triangle tiles of 16x16 grid
    int bj = (int)((sqrtf(8.0f * (float)t + 1.0f) - 1.0f) * 0.5f);
    while ((bj + 1) * (bj + 2) / 2 <= t) ++bj;
    while (bj * (bj + 1) / 2 > t) --bj;
    int bi = t - bj * (bj + 1) / 2;
    int a0 = bi * 128, b0 = bj * 128;
    int n0 = blockIdx.y * (NN / 8);
    int n1 = n0 + NN / 8;
    int tid = threadIdx.x;
    int lr = tid / 32, lc = (tid % 32) * 4;   // staging: row 0..7, col quad
    int tr = tid / 16, tc = tid % 16;         // 16x16 thread grid, 8x8 each
    float acc[8][8] = {};
    for (int n = n0; n < n1; n += 16) {
        *(float4*)&As[lr][lc]     = *(const float4*)&x[(size_t)(n + lr) * DD + a0 + lc];
        *(float4*)&As[lr + 8][lc] = *(const float4*)&x[(size_t)(n + lr + 8) * DD + a0 + lc];
        *(float4*)&Bs[lr][lc]     = *(const float4*)&x[(size_t)(n + lr) * DD + b0 + lc];
        *(float4*)&Bs[lr + 8][lc] = *(const float4*)&x[(size_t)(n + lr + 8) * DD + b0 + lc];
        __syncthreads();
        for (int kk = 0; kk < 16; ++kk) {
            float a[8], b[8];
            *(float4*)&a[0] = *(const float4*)&As[kk][tr * 8];
            *(float4*)&a[4] = *(const float4*)&As[kk][tr * 8 + 4];
            *(float4*)&b[0] = *(const float4*)&Bs[kk][tc * 8];
            *(float4*)&b[4] = *(const float4*)&Bs[kk][tc * 8 + 4];
            for (int i = 0; i < 8; ++i)
                for (int j = 0; j < 8; ++j)
                    acc[i][j] += a[i] * b[j];
        }
        __syncthreads();
    }
    for (int i = 0; i < 8; ++i) {
        int gr = a0 + tr * 8 + i;
        for (int j = 0; j < 8; ++j)
            atomicAdd(&G[(size_t)gr * DD + b0 + tc * 8 + j], acc[i][j]);
    }
}

// ---------- mirror upper 128-tiles to lower ----------
__global__ void kmirror(float* __restrict__ G) {
    __shared__ float tile[64][65];
    int bi = blockIdx.x, bj = blockIdx.y;
    if (bi >= bj) return;
    int tx = threadIdx.x % 64;
    int ty = threadIdx.x / 64;                // 0..3
    for (int si = 0; si < 2; ++si)
        for (int sj = 0; sj < 2; ++sj) {
            int r0 = bi * 128 + si * 64, c0 = bj * 128 + sj * 64;
            __syncthreads();
            for (int r = ty; r < 64; r += 4)
                tile[r][tx] = G[(size_t)(r0 + r) * DD + c0 + tx];
            __syncthreads();
            for (int r = ty; r < 64; r += 4)
                G[(size_t)(c0 + r) * DD + r0 + tx] = tile[tx][r];
        }
}

// ---------- persistent K-loop: 256 blocks, 2 G-rows per wave ----------
__global__ void __launch_bounds__(256)
kloop(float* __restrict__ G, const float* __restrict__ V0T,
      const float* __restrict__ d0, float* __restrict__ Vn,
      float* __restrict__ g, float* __restrict__ s,
      unsigned* __restrict__ arrive, unsigned* __restrict__ gen) {
    __shared__ float bufU[DD];   // u (phase A) -> vn (phase B)
    __shared__ float bufH[DD];   // h = g - c*vn
    __shared__ float bufW[DD];   // v0_next (prefetched during phase A)
    __shared__ float sdata[4];
    int tid = threadIdx.x;
    int wave = tid >> 6, lane = tid & 63;
    int row0 = blockIdx.x * 8 + wave * 2;        // this wave's 2 rows
    float* Gr0 = G + (size_t)row0 * DD;          // block-private: plain, L2-dirty
    float* Gr1 = Gr0 + DD;
    unsigned it = 0;

    // init: s = G v0_0
    for (int t = 0; t < 8; ++t) bufW[tid + t * 256] = V0T[tid + t * 256];
    __syncthreads();
    {
        float a0 = 0.f, a1 = 0.f;
        for (int c = 0; c < 8; ++c) {
            int idx = lane * 4 + c * 256;
            float4 q0 = *(const float4*)(Gr0 + idx);
            float4 q1 = *(const float4*)(Gr1 + idx);
            float4 w  = *(const float4*)(bufW + idx);
            a0 += q0.x * w.x + q0.y * w.y + q0.z * w.z + q0.w * w.w;
            a1 += q1.x * w.x + q1.y * w.y + q1.z * w.z + q1.w * w.w;
        }
        for (int off = 32; off > 0; off >>= 1) {
            a0 += __shfl_down(a0, off, 64);
            a1 += __shfl_down(a1, off, 64);
        }
        if (lane == 0) { astore(&s[row0], a0); astore(&s[row0 + 1], a1); }
    }
    gbar(arrive, gen, ++it);

    for (int k = 0; k < KK; ++k) {
        // ---- phase A: u = 0.5 v + (0.5/d) s; vn = u/||u||; g = G vn ----
        const float* v = V0T + (size_t)k * DD;
        float cf = 0.5f / d0[k];
        float acc = 0.f;
        for (int t = 0; t < 8; ++t) {
            int j = tid + t * 256;
            float uj = 0.5f * v[j] + cf * aload(&s[j]);
            bufU[j] = uj;
            acc += uj * uj;
        }
        float n2 = blockReduceSum(acc, sdata);   // barrier covers bufU writes
        float inv = 1.0f / sqrtf(n2);            // identical in every block
        if (blockIdx.x == 0) {
            for (int t = 0; t < 8; ++t) {
                int j = tid + t * 256;
                Vn[(size_t)k * DD + j] = bufU[j] * inv;
            }
        }
        {
            float a0 = 0.f, a1 = 0.f;
            for (int c = 0; c < 8; ++c) {
                int idx = lane * 4 + c * 256;
                float4 q0 = *(const float4*)(Gr0 + idx);
                float4 q1 = *(const float4*)(Gr1 + idx);
                float4 u  = *(const float4*)(bufU + idx);
                a0 += q0.x * u.x + q0.y * u.y + q0.z * u.z + q0.w * u.w;
                a1 += q1.x * u.x + q1.y * u.y + q1.z * u.z + q1.w * u.w;
            }
            for (int off = 32; off > 0; off >>= 1) {
                a0 += __shfl_down(a0, off, 64);
                a1 += __shfl_down(a1, off, 64);
            }
            if (lane == 0) { astore(&g[row0], a0 * inv); astore(&g[row0 + 1], a1 * inv); }
        }
        // prefetch v0_{k+1} into LDS — overlaps the barrier wait
        if (k < KK - 1) {
            for (int t = 0; t < 8; ++t) {
                int j = tid + t * 256;
                bufW[j] = V0T[(size_t)(k + 1) * DD + j];
            }
        }
        gbar(arrive, gen, ++it);
        if (k == KK - 1) break;

        // ---- phase B: G -= vn h^T + g vn^T; fused s_next = G' v0_{k+1} ----
        float accc = 0.f;
        for (int t = 0; t < 8; ++t) {
            int j = tid + t * 256;
            float vnj = bufU[j] * inv;           // vn from local u (no global read)
            bufU[j] = vnj;
            float gj = aload(&g[j]);
            bufH[j] = gj;
            accc += vnj * gj;
        }
        float c2 = blockReduceSum(accc, sdata);  // barrier covers buf writes
        for (int t = 0; t < 8; ++t) {
            int j = tid + t * 256;
            bufH[j] -= c2 * bufU[j];
        }
        __syncthreads();
        float vn0 = bufU[row0],  vn1 = bufU[row0 + 1];
        float gg0 = bufH[row0] + c2 * vn0;       // = g[row0], from LDS
        float gg1 = bufH[row0 + 1] + c2 * vn1;
        float a0 = 0.f, a1 = 0.f;
        for (int cc = 0; cc < 8; ++cc) {
            int idx = lane * 4 + cc * 256;
            float4 Q0 = *(float4*)(Gr0 + idx);
            float4 Q1 = *(float4*)(Gr1 + idx);
            float4 h  = *(const float4*)(bufH + idx);
            float4 vq = *(const float4*)(bufU + idx);
            float4 w  = *(const float4*)(bufW + idx);
            Q0.x = Q0.x - vn0 * h.x - gg0 * vq.x;
            Q0.y = Q0.y - vn0 * h.y - gg0 * vq.y;
            Q0.z = Q0.z - vn0 * h.z - gg0 * vq.z;
            Q0.w = Q0.w - vn0 * h.w - gg0 * vq.w;
            Q1.x = Q1.x - vn1 * h.x - gg1 * vq.x;
            Q1.y = Q1.y - vn1 * h.y - gg1 * vq.y;
            Q1.z = Q1.z - vn1 * h.z - gg1 * vq.z;
            Q1.w = Q1.w - vn1 * h.w - gg1 * vq.w;
            a0 += Q0.x * w.x + Q0.y * w.y + Q0.z * w.z + Q0.w * w.w;
            a1 += Q1.x * w.x + Q1.y * w.y + Q1.z * w.z + Q1.w * w.w;
            *(float4*)(Gr0 + idx) = Q0;
            *(float4*)(Gr1 + idx) = Q1;
        }
        for (int off = 32; off > 0; off >>= 1) {
            a0 += __shfl_down(a0, off, 64);
            a1 += __shfl_down(a1, off, 64);
        }
        if (lane == 0) { astore(&s[row0], a0); astore(&s[row0 + 1], a1); }
        gbar(arrive, gen, ++it);
    }
}

// ---------- out[N][K] = x . Vn^T  (64x64 tiles, fp32) ----------
__global__ void kout(const float* __restrict__ x, const float* __restrict__ Vn,
                     float* __restrict__ out) {
    __shared__ float As[32][68];
    __shared__ float Bs[32][68];
    int i0 = blockIdx.x * 64;
    int k0 = blockIdx.y * 64;
    int tid = threadIdx.x;
    int tr = tid / 16;
    int tc = tid % 16;
    float acc[4][4] = {};
    for (int j0 = 0; j0 < DD; j0 += 32) {
        int c = tid % 32;
        int r0 = tid / 32;
        for (int pass = 0; pass < 8; ++pass) {
            int rr = r0 + pass * 8;
            As[c][rr] = x[(size_t)(i0 + rr) * DD + j0 + c];
            Bs[c][rr] = Vn[(size_t)(k0 + rr) * DD + j0 + c];
        }
        __syncthreads();
        for (int kk = 0; kk < 32; ++kk) {
            float4 a4 = *(const float4*)&As[kk][tr * 4];
            float4 b4 = *(const float4*)&Bs[kk][tc * 4];
            float a[4] = {a4.x, a4.y, a4.z, a4.w};
            float b[4] = {b4.x, b4.y, b4.z, b4.w};
            for (int ar = 0; ar < 4; ++ar)
                for (int bc = 0; bc < 4; ++bc)
                    acc[ar][bc] += a[ar] * b[bc];
        }
        __syncthreads();
    }
    for (int ar = 0; ar < 4; ++ar) {
        float4 o = make_float4(acc[ar][0], acc[ar][1], acc[ar][2], acc[ar][3]);
        *(float4*)&out[(size_t)(i0 + tr * 4 + ar) * KK + k0 + tc * 4] = o;
    }
}

extern "C" void kernel_launch(void* const* d_in, const int* in_sizes, int n_in,
                              void* d_out, int out_size, void* d_ws, size_t ws_size,
                              hipStream_t stream) {
    const float* x  = (const float*)d_in[0];   // [N*D]
    const float* V0 = (const float*)d_in[1];   // [D*K]
    float* out = (float*)d_out;                // [N*K]

    float* G   = (float*)d_ws;                 // D*D
    float* V0T = G + (size_t)DD * DD;          // K*D
    float* Vn  = V0T + (size_t)KK * DD;        // K*D
    float* g   = Vn + (size_t)KK * DD;         // D
    float* sb  = g + DD;                       // D
    float* d0  = sb + DD;                      // K
    unsigned* arrive = (unsigned*)(d0 + KK);   // LOOP_BLOCKS flags
    unsigned* gen    = arrive + LOOP_BLOCKS + 64;  // separate cache line

    hipMemsetAsync(G, 0, (size_t)DD * DD * sizeof(float), stream);
    hipMemsetAsync(arrive, 0, (LOOP_BLOCKS + 128) * sizeof(unsigned), stream);
    ktranspose<<<dim3(DD / 32, KK / 32), 256, 0, stream>>>(V0, V0T);
    kd0<<<KK, 256, 0, stream>>>(V0T, d0);
    ksyrk<<<dim3(136, 8), 256, 0, stream>>>(x, G);
    kmirror<<<dim3(16, 16), 256, 0, stream>>>(G);

    void* args[] = {(void*)&G, (void*)&V0T, (void*)&d0, (void*)&Vn,
                    (void*)&g, (void*)&sb, (void*)&arrive, (void*)&gen};
    hipLaunchCooperativeKernel((void*)kloop, dim3(LOOP_BLOCKS), dim3(256),
                               args, 0, stream);

    kout<<<dim3(NN / 64, KK / 64), 256, 0, stream>>>(x, Vn, out);
}

// Round 7
// 4419.751 us; speedup vs baseline: 8.1531x; 1.1785x over previous
//
#include <hip/hip_runtime.h>
#include <math.h>

#define NN 8192
#define DD 2048
#define KK 256
#define LOOP_BLOCKS 256   // 1 block/CU; 8 G-rows per block, G held in VGPRs

// ---------- block reduce (256 threads, wave=64) ----------
__device__ __forceinline__ float blockReduceSum(float val, float* sdata) {
    for (int off = 32; off > 0; off >>= 1)
        val += __shfl_down(val, off, 64);
    int wid = threadIdx.x >> 6;
    int lane = threadIdx.x & 63;
    __syncthreads();                 // protect sdata from previous use
    if (lane == 0) sdata[wid] = val;
    __syncthreads();
    return sdata[0] + sdata[1] + sdata[2] + sdata[3];
}

__device__ __forceinline__ void blockReduce3(float& a, float& b, float& c, float* sdata) {
    for (int off = 32; off > 0; off >>= 1) {
        a += __shfl_down(a, off, 64);
        b += __shfl_down(b, off, 64);
        c += __shfl_down(c, off, 64);
    }
    int wid = threadIdx.x >> 6;
    int lane = threadIdx.x & 63;
    __syncthreads();
    if (lane == 0) { sdata[wid] = a; sdata[4 + wid] = b; sdata[8 + wid] = c; }
    __syncthreads();
    a = sdata[0] + sdata[1] + sdata[2] + sdata[3];
    b = sdata[4] + sdata[5] + sdata[6] + sdata[7];
    c = sdata[8] + sdata[9] + sdata[10] + sdata[11];
}

// ---------- cross-block primitives: RELAXED agent atomics only ----------
__device__ __forceinline__ float aload(const float* p) {
    return __hip_atomic_load(p, __ATOMIC_RELAXED, __HIP_MEMORY_SCOPE_AGENT);
}
__device__ __forceinline__ void astore(float* p, float v) {
    __hip_atomic_store(p, v, __ATOMIC_RELAXED, __HIP_MEMORY_SCOPE_AGENT);
}
__device__ __forceinline__ unsigned aloadu(const unsigned* p) {
    return __hip_atomic_load(p, __ATOMIC_RELAXED, __HIP_MEMORY_SCOPE_AGENT);
}
__device__ __forceinline__ void astoreu(unsigned* p, unsigned v) {
    __hip_atomic_store(p, v, __ATOMIC_RELAXED, __HIP_MEMORY_SCOPE_AGENT);
}

// Two-hop grid barrier, monotonic index, relaxed atomics only.
__device__ __forceinline__ void gbar(unsigned* __restrict__ arrive,
                                     unsigned* __restrict__ gen, unsigned it) {
    __atomic_signal_fence(__ATOMIC_SEQ_CST);
    __builtin_amdgcn_s_waitcnt(0);        // drain this wave's t/z publishes
    __syncthreads();
    int tid = threadIdx.x;
    if (tid == 0)
        astoreu(&arrive[blockIdx.x], it);
    if (blockIdx.x == 0) {
        if (tid < 64) {
            int base = tid * 4;
            for (;;) {
                unsigned a0 = aloadu(&arrive[base + 0]);
                unsigned a1 = aloadu(&arrive[base + 1]);
                unsigned a2 = aloadu(&arrive[base + 2]);
                unsigned a3 = aloadu(&arrive[base + 3]);
                if (a0 >= it && a1 >= it && a2 >= it && a3 >= it) break;
                __builtin_amdgcn_s_sleep(1);
            }
        }
        __syncthreads();
        if (tid == 0) astoreu(gen, it);
    } else {
        if (tid == 0) {
            while (aloadu(gen) < it)
                __builtin_amdgcn_s_sleep(1);
        }
        __syncthreads();
    }
    __atomic_signal_fence(__ATOMIC_SEQ_CST);
}

// ---------- V0 [D][K] -> V0T [K][D] ----------
__global__ void ktranspose(const float* __restrict__ V0, float* __restrict__ V0T) {
    __shared__ float tile[32][33];
    int bx = blockIdx.x;
    int by = blockIdx.y;
    int tx = threadIdx.x % 32;
    int ty = threadIdx.x / 32;
    for (int r = ty; r < 32; r += 8)
        tile[r][tx] = V0[(size_t)(bx * 32 + r) * KK + by * 32 + tx];
    __syncthreads();
    for (int r = ty; r < 32; r += 8)
        V0T[(size_t)(by * 32 + r) * DD + bx * 32 + tx] = tile[tx][r];
}

// ---------- d0[k] = ||V0[:,k]|| ----------
__global__ void kd0(const float* __restrict__ V0T, float* __restrict__ d0) {
    __shared__ float sdata[12];
    int k = blockIdx.x;
    float acc = 0.f;
    for (int j = threadIdx.x; j < DD; j += 256) {
        float v = V0T[(size_t)k * DD + j];
        acc += v * v;
    }
    float s = blockReduceSum(acc, sdata);
    if (threadIdx.x == 0) d0[k] = sqrtf(s);
}

// ---------- G += x_chunk^T x_chunk, 128x128 triangle tiles, 8 N-chunks ----------
__global__ __launch_bounds__(256) void ksyrk(const float* __restrict__ x,
                                             float* __restrict__ G) {
    __shared__ float As[16][132];
    __shared__ float Bs[16][132];
    int t = blockIdx.x;                       // 0..135 triangle tiles of 16x16 grid
    int bj = (int)((sqrtf(8.0f * (float)t + 1.0f) - 1.0f) * 0.5f);
    while ((bj + 1) * (bj + 2) / 2 <= t) ++bj;
    while (bj * (bj + 1) / 2 > t) --bj;
    int bi = t - bj * (bj + 1) / 2;
    int a0 = bi * 128, b0 = bj * 128;
    int n0 = blockIdx.y * (NN / 8);
    int n1 = n0 + NN / 8;
    int tid = threadIdx.x;
    int lr = tid / 32, lc = (tid % 32) * 4;   // staging: row 0..7, col quad
    int tr = tid / 16, tc = tid % 16;         // 16x16 thread grid, 8x8 each
    float acc[8][8] = {};
    for (int n = n0; n < n1; n += 16) {
        *(float4*)&As[lr][lc]     = *(const float4*)&x[(size_t)(n + lr) * DD + a0 + lc];
        *(float4*)&As[lr + 8][lc] = *(const float4*)&x[(size_t)(n + lr + 8) * DD + a0 + lc];
        *(float4*)&Bs[lr][lc]     = *(const float4*)&x[(size_t)(n + lr) * DD + b0 + lc];
        *(float4*)&Bs[lr + 8][lc] = *(const float4*)&x[(size_t)(n + lr + 8) * DD + b0 + lc];
        __syncthreads();
        for (int kk = 0; kk < 16; ++kk) {
            float a[8], b[8];
            *(float4*)&a[0] = *(const float4*)&As[kk][tr * 8];
            *(float4*)&a[4] = *(const float4*)&As[kk][tr * 8 + 4];
            *(float4*)&b[0] = *(const float4*)&Bs[kk][tc * 8];
            *(float4*)&b[4] = *(const float4*)&Bs[kk][tc * 8 + 4];
            for (int i = 0; i < 8; ++i)
                for (int j = 0; j < 8; ++j)
                    acc[i][j] += a[i] * b[j];
        }
        __syncthreads();
    }
    for (int i = 0; i < 8; ++i) {
        int gr = a0 + tr * 8 + i;
        for (int j = 0; j < 8; ++j)
            atomicAdd(&G[(size_t)gr * DD + b0 + tc * 8 + j], acc[i][j]);
    }
}

// ---------- mirror upper 128-tiles to lower ----------
__global__ void kmirror(float* __restrict__ G) {
    __shared__ float tile[64][65];
    int bi = blockIdx.x, bj = blockIdx.y;
    if (bi >= bj) return;
    int tx = threadIdx.x % 64;
    int ty = threadIdx.x / 64;                // 0..3
    for (int si = 0; si < 2; ++si)
        for (int sj = 0; sj < 2; ++sj) {
            int r0 = bi * 128 + si * 64, c0 = bj * 128 + sj * 64;
            __syncthreads();
            for (int r = ty; r < 64; r += 4)
                tile[r][tx] = G[(size_t)(r0 + r) * DD + c0 + tx];
            __syncthreads();
            for (int r = ty; r < 64; r += 4)
                G[(size_t)(c0 + r) * DD + r0 + tx] = tile[tx][r];
        }
}

// ---------- persistent K-loop: G in registers, 1 barrier/iteration ----------
// Recurrence: s_{k+1} = z - alpha*g - beta*vn,  z = G_k v0_{k+1},
//   alpha = vn.v0_{k+1}, c = vn.g, beta = vn.z - alpha*c, g = G_k vn.
// G update (deferred one iteration): G -= vn h^T + g vn^T, h = g - c vn.
__global__ void __launch_bounds__(256, 1)
kloop(const float* __restrict__ G, const float* __restrict__ V0T,
      const float* __restrict__ d0, float* __restrict__ Vn,
      float* __restrict__ tarr0, float* __restrict__ zarr0,
      float* __restrict__ tarr1, float* __restrict__ zarr1,
      float* __restrict__ s0buf,
      unsigned* __restrict__ arrive, unsigned* __restrict__ gen) {
    __shared__ float L[6][DD];
    __shared__ float sdata[12];
    float* pVN  = L[0];   // vn_{k-1}
    float* pVNn = L[1];   // vn_k
    float* pZH  = L[2];   // gathered z, then h
    float* pTG  = L[3];   // gathered t, then g
    float* pS   = L[4];   // s
    float* pW   = L[5];   // current v0 row
    int tid = threadIdx.x;
    int sub = tid & 31;          // column chunk 0..31
    int rloc = tid >> 5;         // row 0..7 within block
    int c0 = sub * 64;
    int grow = blockIdx.x * 8 + rloc;
    unsigned it = 0;

    // G rows -> registers (64 VGPRs): row grow, cols c0..c0+63
    float4 Greg[16];
    {
        const float* Gr = G + (size_t)grow * DD + c0;
#pragma unroll
        for (int i = 0; i < 16; ++i) Greg[i] = *(const float4*)(Gr + 4 * i);
    }
    // v0_0 -> pW
    for (int tt = 0; tt < 8; ++tt) pW[tid + tt * 256] = V0T[tid + tt * 256];
    __syncthreads();
    // init: s0 = G v0_0
    {
        float t0 = 0.f;
#pragma unroll
        for (int i = 0; i < 16; ++i) {
            float4 w4 = *(const float4*)&pW[c0 + 4 * i];
            float4 Gq = Greg[i];
            t0 += Gq.x * w4.x + Gq.y * w4.y + Gq.z * w4.z + Gq.w * w4.w;
        }
        for (int off = 16; off > 0; off >>= 1) t0 += __shfl_down(t0, off, 64);
        if (sub == 0) astore(&s0buf[grow], t0);
    }
    gbar(arrive, gen, ++it);

    float inv_prev, cf_prev;
    {
        // gather s0; vn_0; publish t0 = G s0, z0 = G v0_1  (parity 0)
        for (int tt = 0; tt < 8; ++tt) { int j = tid + tt * 256; pS[j] = aload(&s0buf[j]); }
        float cf0 = 0.5f / d0[0];
        float u_reg[8]; float aN = 0.f;
        for (int tt = 0; tt < 8; ++tt) { int j = tid + tt * 256;
            float u = 0.5f * pW[j] + cf0 * pS[j]; u_reg[tt] = u; aN += u * u; }
        float n2 = blockReduceSum(aN, sdata);
        float inv = 1.0f / sqrtf(n2);
        for (int tt = 0; tt < 8; ++tt) { int j = tid + tt * 256;
            float vnv = u_reg[tt] * inv;
            pVN[j] = vnv;
            if (blockIdx.x == 0) Vn[j] = vnv;
            pW[j] = V0T[DD + j];                     // prefetch v0_1
        }
        __syncthreads();
        float t = 0.f, z = 0.f;
#pragma unroll
        for (int i = 0; i < 16; ++i) {
            int jj = c0 + 4 * i;
            float4 s4 = *(const float4*)&pS[jj];
            float4 w4 = *(const float4*)&pW[jj];
            float4 Gq = Greg[i];
            t += Gq.x * s4.x + Gq.y * s4.y + Gq.z * s4.z + Gq.w * s4.w;
            z += Gq.x * w4.x + Gq.y * w4.y + Gq.z * w4.z + Gq.w * w4.w;
        }
        for (int off = 16; off > 0; off >>= 1) {
            t += __shfl_down(t, off, 64); z += __shfl_down(z, off, 64);
        }
        if (sub == 0) { astore(&tarr0[grow], t); astore(&zarr0[grow], z); }
        inv_prev = inv; cf_prev = cf0;
    }
    gbar(arrive, gen, ++it);

    for (int k = 1; k < KK; ++k) {
        const int par = k & 1;
        float* tin  = par ? tarr0 : tarr1;   // published at k-1 (parity (k-1)&1)
        float* zin  = par ? zarr0 : zarr1;
        float* tout = par ? tarr1 : tarr0;   // published at k (parity k&1)
        float* zout = par ? zarr1 : zarr0;

        // gather t_{k-1}, z_{k-1}; compute g; scalar partials
        float tg[8], zg[8];
        for (int tt = 0; tt < 8; ++tt) { int j = tid + tt * 256;
            tg[tt] = aload(&tin[j]); zg[tt] = aload(&zin[j]); }
        float aA = 0.f, aC = 0.f, aG = 0.f;
        for (int tt = 0; tt < 8; ++tt) { int j = tid + tt * 256;
            float vnv = pVN[j];
            aA += vnv * pW[j];                                   // vn . v0_k
            float gv = (0.5f * pS[j] + cf_prev * tg[tt]) * inv_prev;
            pTG[j] = gv;
            aC += vnv * gv;                                      // vn . g
            aG += vnv * zg[tt];                                  // vn . z
            pZH[j] = zg[tt];
        }
        blockReduce3(aA, aC, aG, sdata);
        float alpha = aA, cc = aC, beta = aG - aA * aC;

        // s_k, h, u, vn_k
        float cfk = 0.5f / d0[k];
        float u_reg[8]; float aN = 0.f;
        for (int tt = 0; tt < 8; ++tt) { int j = tid + tt * 256;
            float vnv = pVN[j]; float gv = pTG[j]; float zv = pZH[j];
            float sv = zv - alpha * gv - beta * vnv;
            pS[j] = sv;
            pZH[j] = gv - cc * vnv;                              // h
            float u = 0.5f * pW[j] + cfk * sv;
            u_reg[tt] = u; aN += u * u;
        }
        float n2 = blockReduceSum(aN, sdata);
        float invk = 1.0f / sqrtf(n2);
        for (int tt = 0; tt < 8; ++tt) { int j = tid + tt * 256;
            float vnv = u_reg[tt] * invk;
            pVNn[j] = vnv;
            if (blockIdx.x == 0) Vn[(size_t)k * DD + j] = vnv;
            if (k < KK - 1) pW[j] = V0T[(size_t)(k + 1) * DD + j];  // prefetch
        }
        if (k == KK - 1) break;
        __syncthreads();

        // register-G pass: deferred rank-2 update + t = G s, z = G v0_{k+1}
        {
            float vnr = pVN[grow], gr = pTG[grow];
            float t = 0.f, z = 0.f;
#pragma unroll
            for (int i = 0; i < 16; ++i) {
                int jj = c0 + 4 * i;
                float4 h4 = *(const float4*)&pZH[jj];
                float4 v4 = *(const float4*)&pVN[jj];
                float4 s4 = *(const float4*)&pS[jj];
                float4 w4 = *(const float4*)&pW[jj];
                float4 Gq = Greg[i];
                Gq.x -= vnr * h4.x + gr * v4.x;
                Gq.y -= vnr * h4.y + gr * v4.y;
                Gq.z -= vnr * h4.z + gr * v4.z;
                Gq.w -= vnr * h4.w + gr * v4.w;
                Greg[i] = Gq;
                t += Gq.x * s4.x + Gq.y * s4.y + Gq.z * s4.z + Gq.w * s4.w;
                z += Gq.x * w4.x + Gq.y * w4.y + Gq.z * w4.z + Gq.w * w4.w;
            }
            for (int off = 16; off > 0; off >>= 1) {
                t += __shfl_down(t, off, 64); z += __shfl_down(z, off, 64);
            }
            if (sub == 0) { astore(&tout[grow], t); astore(&zout[grow], z); }
        }
        gbar(arrive, gen, ++it);
        float* tmp = pVN; pVN = pVNn; pVNn = tmp;
        inv_prev = invk; cf_prev = cfk;
    }
}

// ---------- out[N][K] = x . Vn^T  (64x64 tiles, fp32) ----------
__global__ void kout(const float* __restrict__ x, const float* __restrict__ Vn,
                     float* __restrict__ out) {
    __shared__ float As[32][68];
    __shared__ float Bs[32][68];
    int i0 = blockIdx.x * 64;
    int k0 = blockIdx.y * 64;
    int tid = threadIdx.x;
    int tr = tid / 16;
    int tc = tid % 16;
    float acc[4][4] = {};
    for (int j0 = 0; j0 < DD; j0 += 32) {
        int c = tid % 32;
        int r0 = tid / 32;
        for (int pass = 0; pass < 8; ++pass) {
            int rr = r0 + pass * 8;
            As[c][rr] = x[(size_t)(i0 + rr) * DD + j0 + c];
            Bs[c][rr] = Vn[(size_t)(k0 + rr) * DD + j0 + c];
        }
        __syncthreads();
        for (int kk = 0; kk < 32; ++kk) {
            float4 a4 = *(const float4*)&As[kk][tr * 4];
            float4 b4 = *(const float4*)&Bs[kk][tc * 4];
            float a[4] = {a4.x, a4.y, a4.z, a4.w};
            float b[4] = {b4.x, b4.y, b4.z, b4.w};
            for (int ar = 0; ar < 4; ++ar)
                for (int bc = 0; bc < 4; ++bc)
                    acc[ar][bc] += a[ar] * b[bc];
        }
        __syncthreads();
    }
    for (int ar = 0; ar < 4; ++ar) {
        float4 o = make_float4(acc[ar][0], acc[ar][1], acc[ar][2], acc[ar][3]);
        *(float4*)&out[(size_t)(i0 + tr * 4 + ar) * KK + k0 + tc * 4] = o;
    }
}

extern "C" void kernel_launch(void* const* d_in, const int* in_sizes, int n_in,
                              void* d_out, int out_size, void* d_ws, size_t ws_size,
                              hipStream_t stream) {
    const float* x  = (const float*)d_in[0];   // [N*D]
    const float* V0 = (const float*)d_in[1];   // [D*K]
    float* out = (float*)d_out;                // [N*K]

    float* G    = (float*)d_ws;                // D*D
    float* V0T  = G + (size_t)DD * DD;         // K*D
    float* Vn   = V0T + (size_t)KK * DD;       // K*D
    float* d0   = Vn + (size_t)KK * DD;        // K
    float* t0   = d0 + KK;                     // D
    float* z0   = t0 + DD;                     // D
    float* t1   = z0 + DD;                     // D
    float* z1   = t1 + DD;                     // D
    float* s0b  = z1 + DD;                     // D
    unsigned* arrive = (unsigned*)(s0b + DD);  // LOOP_BLOCKS flags
    unsigned* gen    = arrive + LOOP_BLOCKS + 64;  // separate line

    hipMemsetAsync(G, 0, (size_t)DD * DD * sizeof(float), stream);
    hipMemsetAsync(arrive, 0, (LOOP_BLOCKS + 128) * sizeof(unsigned), stream);
    ktranspose<<<dim3(DD / 32, KK / 32), 256, 0, stream>>>(V0, V0T);
    kd0<<<KK, 256, 0, stream>>>(V0T, d0);
    ksyrk<<<dim3(136, 8), 256, 0, stream>>>(x, G);
    kmirror<<<dim3(16, 16), 256, 0, stream>>>(G);

    void* args[] = {(void*)&G, (void*)&V0T, (void*)&d0, (void*)&Vn,
                    (void*)&t0, (void*)&z0, (void*)&t1, (void*)&z1,
                    (void*)&s0b, (void*)&arrive, (void*)&gen};
    hipLaunchCooperativeKernel((void*)kloop, dim3(LOOP_BLOCKS), dim3(256),
                               args, 0, stream);

    kout<<<dim3(NN / 64, KK / 64), 256, 0, stream>>>(x, Vn, out);
}